// Round 1
// baseline (243.775 us; speedup 1.0000x reference)
//
#include <hip/hip_runtime.h>
#include <math.h>

#define D_MODEL 1024
#define NMOD 8
#define BATCH 8
#define NNODE 8192
#define PI_F 3.14159265358979323846f
#define MAXT 3.0f

#define KT 32      // K tile
#define NB 256     // nodes per block
#define NBP 260    // padded LDS row stride (multiple of 4 for b128 alignment)

// ---------------- kernel 0: transpose W [64][1024] -> WT [1024][64]
__global__ void transpose_w(const float* __restrict__ W, float* __restrict__ WT) {
    int idx = blockIdx.x * 256 + threadIdx.x;   // 65536 total
    int k = idx >> 6, j = idx & 63;
    WT[idx] = W[j * D_MODEL + k];
}

// ---------------- kernel A: GEMM + activations + group-sum atomics
__global__ __launch_bounds__(256) void gemm_act(
    const float* __restrict__ feats, const float* __restrict__ WT,
    const float* __restrict__ bias,
    float* __restrict__ ew_out, float* __restrict__ sp_out,
    float* __restrict__ sums)
{
    __shared__ __align__(16) float lf[KT][NBP];
    const int tid  = threadIdx.x;
    const int lane = tid & 63;
    const int wv   = __builtin_amdgcn_readfirstlane(tid >> 6);  // wave id 0..3, uniform
    const int nodeBase = blockIdx.x * NB;

    float acc[4][16];
    #pragma unroll
    for (int a = 0; a < 4; ++a)
        #pragma unroll
        for (int j = 0; j < 16; ++j) acc[a][j] = 0.f;

    const int rrow = tid >> 3;   // 0..31
    const int slot = tid & 7;    // 0..7   (8 float4 slots cover KT=32 floats)

    for (int k0 = 0; k0 < D_MODEL; k0 += KT) {
        __syncthreads();
        // stage feats tile [NB][KT] -> LDS transposed [KT][NB]
        #pragma unroll
        for (int p = 0; p < 8; ++p) {
            int row = p * 32 + rrow;
            const float4 f = *reinterpret_cast<const float4*>(
                &feats[(size_t)(nodeBase + row) * D_MODEL + k0 + slot * 4]);
            lf[slot * 4 + 0][row] = f.x;
            lf[slot * 4 + 1][row] = f.y;
            lf[slot * 4 + 2][row] = f.z;
            lf[slot * 4 + 3][row] = f.w;
        }
        __syncthreads();

        const float* wk = WT + (size_t)k0 * 64 + wv * 16;  // uniform -> s_load
        #pragma unroll 4
        for (int kk = 0; kk < KT; ++kk) {
            float4 f = *reinterpret_cast<const float4*>(&lf[kk][lane * 4]);
            #pragma unroll
            for (int j = 0; j < 16; ++j) {
                float w = wk[kk * 64 + j];
                acc[0][j] = fmaf(f.x, w, acc[0][j]);
                acc[1][j] = fmaf(f.y, w, acc[1][j]);
                acc[2][j] = fmaf(f.z, w, acc[2][j]);
                acc[3][j] = fmaf(f.w, w, acc[3][j]);
            }
        }
    }

    // bias
    #pragma unroll
    for (int j = 0; j < 16; ++j) {
        float bj = bias[wv * 16 + j];
        #pragma unroll
        for (int a = 0; a < 4; ++a) acc[a][j] += bj;
    }

    const int bidx = nodeBase / NNODE;           // batch index (block never straddles)
    const int nInB = nodeBase % NNODE;           // + 4*lane + a gives node within batch

    float red[2][8];
    #pragma unroll
    for (int ml = 0; ml < 2; ++ml)
        #pragma unroll
        for (int v = 0; v < 8; ++v) red[ml][v] = 0.f;

    #pragma unroll
    for (int ml = 0; ml < 2; ++ml) {
        const int m = wv * 2 + ml;
        float ewv[4], spv[4];
        #pragma unroll
        for (int a = 0; a < 4; ++a) {
            const float* pa = &acc[a][ml * 8];
            float al = pa[0], sl = pa[1];
            float ax = pa[2], ay = pa[3], az = pa[4];
            float tx = pa[5], ty = pa[6], tz = pa[7];

            float ew = expf(al);                       // softmax numerator (no max-sub; logits ~N(0,1))
            float sp = 1.f / (1.f + expf(-sl));        // sigmoid

            float n0  = sqrtf(ax * ax + ay * ay + az * az);
            float inv = 1.f / fmaxf(n0, 1e-12f);       // _normalize clip
            float ang = tanhf(n0) * PI_F;
            float hf  = 0.5f * ang;
            float shoa = (ang < 1e-6f) ? (0.5f - ang * ang * (1.f / 48.f))
                                       : (sinf(hf) / ang);
            float qw = cosf(hf);
            float fac = inv * ang * shoa;
            float qx = ax * fac, qy = ay * fac, qz = az * fac;

            float ttx = tanhf(tx) * MAXT, tty = tanhf(ty) * MAXT, ttz = tanhf(tz) * MAXT;

            ewv[a] = ew; spv[a] = sp;
            red[ml][0] += sp;
            red[ml][1] += sp * qw; red[ml][2] += sp * qx;
            red[ml][3] += sp * qy; red[ml][4] += sp * qz;
            red[ml][5] += sp * ttx; red[ml][6] += sp * tty; red[ml][7] += sp * ttz;
        }
        size_t base = ((size_t)(bidx * NMOD + m)) * NNODE + nInB + 4 * lane;
        *reinterpret_cast<float4*>(&ew_out[base]) = make_float4(ewv[0], ewv[1], ewv[2], ewv[3]);
        *reinterpret_cast<float4*>(&sp_out[base]) = make_float4(spv[0], spv[1], spv[2], spv[3]);
    }

    // wave-reduce the 16 partials, one atomicAdd per value from lane 0
    #pragma unroll
    for (int ml = 0; ml < 2; ++ml) {
        const int m = wv * 2 + ml;
        #pragma unroll
        for (int v = 0; v < 8; ++v) {
            float x = red[ml][v];
            #pragma unroll
            for (int o = 32; o > 0; o >>= 1) x += __shfl_down(x, o);
            if (lane == 0) atomicAdd(&sums[((size_t)(bidx * NMOD + m)) * 8 + v], x);
        }
    }
}

// ---------------- kernel B: sequential 8-module scan, one block per batch
__global__ __launch_bounds__(1024) void scan_coords(
    const float* __restrict__ coords,
    const float* __restrict__ ew_in, const float* __restrict__ sp_in,
    const float* __restrict__ sums, float* __restrict__ out)
{
    const int b   = blockIdx.x;
    const int tid = threadIdx.x;
    const int lane = tid & 63, wid = tid >> 6;
    __shared__ float redbuf[16 * 4];
    __shared__ float bcast[4];

    float cx[8], cy[8], cz[8];
    #pragma unroll
    for (int i = 0; i < 8; ++i) {
        int n = i * 1024 + tid;
        const float* cp = &coords[((size_t)b * NNODE + n) * 3];
        cx[i] = cp[0]; cy[i] = cp[1]; cz[i] = cp[2];
    }

    for (int m = 0; m < NMOD; ++m) {
        const float* ewp = &ew_in[((size_t)b * NMOD + m) * NNODE];
        const float* spp = &sp_in[((size_t)b * NMOD + m) * NNODE];
        float spl[8];
        float se = 0.f, sx = 0.f, sy = 0.f, sz = 0.f;
        #pragma unroll
        for (int i = 0; i < 8; ++i) {
            int n = i * 1024 + tid;
            float e = ewp[n];
            spl[i] = spp[n];
            se += e; sx += e * cx[i]; sy += e * cy[i]; sz += e * cz[i];
        }
        // block reduce {se,sx,sy,sz}
        float vals[4] = {se, sx, sy, sz};
        #pragma unroll
        for (int v = 0; v < 4; ++v) {
            float x = vals[v];
            #pragma unroll
            for (int o = 32; o > 0; o >>= 1) x += __shfl_down(x, o);
            if (lane == 0) redbuf[wid * 4 + v] = x;
        }
        __syncthreads();
        if (tid < 4) {
            float s = 0.f;
            #pragma unroll
            for (int w = 0; w < 16; ++w) s += redbuf[w * 4 + tid];
            bcast[tid] = s;
        }
        __syncthreads();
        const float SE = bcast[0];
        const float AXc = bcast[1] / SE, AYc = bcast[2] / SE, AZc = bcast[3] / SE;

        const float* sm = &sums[((size_t)b * NMOD + m) * 8];
        float s  = fmaxf(sm[0], 1e-8f);
        float qw = sm[1] / s, qx = sm[2] / s, qy = sm[3] / s, qz = sm[4] / s;
        float qn = sqrtf(qw * qw + qx * qx + qy * qy + qz * qz);
        float qi = 1.f / fmaxf(qn, 1e-12f);
        qw *= qi; qx *= qi; qy *= qi; qz *= qi;
        float tgx = sm[5] / s, tgy = sm[6] / s, tgz = sm[7] / s;

        #pragma unroll
        for (int i = 0; i < 8; ++i) {
            float px = cx[i] - AXc, py = cy[i] - AYc, pz = cz[i] - AZc;
            // p' = p + 2*qw*(v x p) + 2*v x (v x p), unit quaternion (qw, v)
            float ux = qy * pz - qz * py;
            float uy = qz * px - qx * pz;
            float uz = qx * py - qy * px;
            float vx = qy * uz - qz * uy;
            float vy = qz * ux - qx * uz;
            float vz = qx * uy - qy * ux;
            float rx = px + 2.f * (qw * ux + vx);
            float ry = py + 2.f * (qw * uy + vy);
            float rz = pz + 2.f * (qw * uz + vz);
            float mx = rx + AXc + tgx, my = ry + AYc + tgy, mz = rz + AZc + tgz;
            float sp = spl[i];
            cx[i] += sp * (mx - cx[i]);
            cy[i] += sp * (my - cy[i]);
            cz[i] += sp * (mz - cz[i]);
        }
        __syncthreads();   // protect redbuf/bcast reuse next module
    }

    #pragma unroll
    for (int i = 0; i < 8; ++i) {
        int n = i * 1024 + tid;
        float* op = &out[((size_t)b * NNODE + n) * 3];
        op[0] = cx[i]; op[1] = cy[i]; op[2] = cz[i];
    }
}

extern "C" void kernel_launch(void* const* d_in, const int* in_sizes, int n_in,
                              void* d_out, int out_size, void* d_ws, size_t ws_size,
                              hipStream_t stream) {
    const float* feats  = (const float*)d_in[0];
    const float* coords = (const float*)d_in[1];
    const float* W      = (const float*)d_in[2];
    const float* bias   = (const float*)d_in[3];
    float* out = (float*)d_out;

    char* ws = (char*)d_ws;
    float* WT   = (float*)(ws);                                   // 256 KB
    float* ew   = (float*)(ws + 262144);                          // 2 MB
    float* sp   = (float*)(ws + 262144 + 2097152);                // 2 MB
    float* sums = (float*)(ws + 262144 + 2 * 2097152);            // 2 KB

    hipMemsetAsync(sums, 0, (size_t)BATCH * NMOD * 8 * sizeof(float), stream);
    transpose_w<<<256, 256, 0, stream>>>(W, WT);
    gemm_act<<<(BATCH * NNODE) / NB, 256, 0, stream>>>(feats, WT, bias, ew, sp, sums);
    scan_coords<<<BATCH, 1024, 0, stream>>>(coords, ew, sp, sums, out);
}

// Round 2
// 130.661 us; speedup vs baseline: 1.8657x; 1.8657x over previous
//
#include <hip/hip_runtime.h>
#include <math.h>

#define D_MODEL 1024
#define NMOD 8
#define BATCH 8
#define NNODE 8192
#define PI_F 3.14159265358979323846f
#define MAXT 3.0f

typedef short bf16x8 __attribute__((ext_vector_type(8)));
typedef float f32x4 __attribute__((ext_vector_type(4)));

__device__ inline unsigned short f2bf_rne(float x) {
    unsigned u = __builtin_bit_cast(unsigned, x);
    unsigned r = u + 0x7FFFu + ((u >> 16) & 1u);
    return (unsigned short)(r >> 16);
}
__device__ inline float bf2f(unsigned short h) {
    unsigned u = ((unsigned)h) << 16;
    return __builtin_bit_cast(float, u);
}

// ---------------- kernel 0: pack W into MFMA B-fragment lane order, bf16 hi/lo
// Entry e = ((ks*4 + g)*2 + s)*64 + lane, 8 ushorts each.
// Lane l, reg r holds B[k = ks*32 + (l>>4)*8 + r][col j = g*16 + (l&15)] = W[j][k]
__global__ void pack_b(const float* __restrict__ W, unsigned short* __restrict__ Bpk) {
    int t = blockIdx.x * 256 + threadIdx.x;   // 16384 total
    int l  = t & 63;
    int s  = (t >> 6) & 1;
    int g  = (t >> 7) & 3;
    int ks = t >> 9;
    int j  = g * 16 + (l & 15);
    int k0 = ks * 32 + ((l >> 4) * 8);
    const float* wp = &W[(size_t)j * D_MODEL + k0];
    unsigned short v[8];
    #pragma unroll
    for (int r = 0; r < 8; ++r) {
        float x = wp[r];
        unsigned short hi = f2bf_rne(x);
        if (s == 0) v[r] = hi;
        else        v[r] = f2bf_rne(x - bf2f(hi));
    }
    bf16x8 pack;
    #pragma unroll
    for (int r = 0; r < 8; ++r) pack[r] = (short)v[r];
    *reinterpret_cast<bf16x8*>(Bpk + (size_t)t * 8) = pack;
}

// ---------------- kernel A: MFMA GEMM (split bf16) + activations + group sums
__global__ __launch_bounds__(256, 4) void gemm_mfma(
    const float* __restrict__ feats, const unsigned short* __restrict__ Bpk,
    const float* __restrict__ bias,
    float* __restrict__ ew_out, float* __restrict__ sp_out,
    float* __restrict__ sums)
{
    __shared__ float pbuf[4][16][68];   // per-wave param transpose buffer
    __shared__ float sacc[64];          // per-block module sums [m][v]

    const int tid  = threadIdx.x;
    const int lane = tid & 63;
    const int wv   = tid >> 6;

    if (tid < 64) sacc[tid] = 0.f;
    __syncthreads();

    const int mt    = blockIdx.x * 4 + wv;   // m-tile (16 nodes)
    const int mbase = mt * 16;
    const float* arow = feats + (size_t)(mbase + (lane & 15)) * D_MODEL + ((lane >> 4) * 8);
    const bf16x8* bp = reinterpret_cast<const bf16x8*>(Bpk);

    f32x4 acc[4];
    #pragma unroll
    for (int g = 0; g < 4; ++g) acc[g] = (f32x4){0.f, 0.f, 0.f, 0.f};

    for (int ks = 0; ks < 32; ++ks) {
        const float4 fa = *reinterpret_cast<const float4*>(arow + ks * 32);
        const float4 fb = *reinterpret_cast<const float4*>(arow + ks * 32 + 4);
        float f[8] = {fa.x, fa.y, fa.z, fa.w, fb.x, fb.y, fb.z, fb.w};
        bf16x8 ahi, alo;
        #pragma unroll
        for (int i = 0; i < 8; ++i) {
            unsigned short h = f2bf_rne(f[i]);
            ahi[i] = (short)h;
            alo[i] = (short)f2bf_rne(f[i] - bf2f(h));
        }
        #pragma unroll
        for (int g = 0; g < 4; ++g) {
            bf16x8 bh = bp[((ks * 4 + g) * 2 + 0) * 64 + lane];
            bf16x8 bl = bp[((ks * 4 + g) * 2 + 1) * 64 + lane];
            acc[g] = __builtin_amdgcn_mfma_f32_16x16x32_bf16(ahi, bh, acc[g], 0, 0, 0);
            acc[g] = __builtin_amdgcn_mfma_f32_16x16x32_bf16(alo, bh, acc[g], 0, 0, 0);
            acc[g] = __builtin_amdgcn_mfma_f32_16x16x32_bf16(ahi, bl, acc[g], 0, 0, 0);
        }
    }

    // params -> per-wave LDS (add bias). D: row=(lane>>4)*4+reg, col=g*16+(lane&15)
    #pragma unroll
    for (int g = 0; g < 4; ++g) {
        float bj = bias[g * 16 + (lane & 15)];
        #pragma unroll
        for (int r = 0; r < 4; ++r)
            pbuf[wv][(lane >> 4) * 4 + r][g * 16 + (lane & 15)] = acc[g][r] + bj;
    }
    // same-wave ds_write -> ds_read: compiler inserts lgkmcnt wait; no barrier needed.

    const int b    = mbase >> 13;     // / 8192
    const int nInB = mbase & 8191;

    #pragma unroll
    for (int h = 0; h < 2; ++h) {
        const int node = lane & 15;
        const int m    = (lane >> 4) + 4 * h;
        const float* pa = &pbuf[wv][node][m * 8];
        float al = pa[0], sl = pa[1];
        float ax = pa[2], ay = pa[3], az = pa[4];
        float tx = pa[5], ty = pa[6], tz = pa[7];

        float ew = expf(al);
        float sp = 1.f / (1.f + expf(-sl));

        float n0  = sqrtf(ax * ax + ay * ay + az * az);
        float inv = 1.f / fmaxf(n0, 1e-12f);
        float ang = tanhf(n0) * PI_F;
        float hf  = 0.5f * ang;
        float shoa = (ang < 1e-6f) ? (0.5f - ang * ang * (1.f / 48.f))
                                   : (sinf(hf) / ang);
        float qw = cosf(hf);
        float fac = inv * ang * shoa;
        float qx = ax * fac, qy = ay * fac, qz = az * fac;

        float ttx = tanhf(tx) * MAXT, tty = tanhf(ty) * MAXT, ttz = tanhf(tz) * MAXT;

        size_t base = ((size_t)(b * NMOD + m)) * NNODE + nInB + node;
        ew_out[base] = ew;
        sp_out[base] = sp;

        float red[8];
        red[0] = sp;
        red[1] = sp * qw; red[2] = sp * qx; red[3] = sp * qy; red[4] = sp * qz;
        red[5] = sp * ttx; red[6] = sp * tty; red[7] = sp * ttz;
        #pragma unroll
        for (int v = 0; v < 8; ++v) {
            #pragma unroll
            for (int o = 1; o < 16; o <<= 1) red[v] += __shfl_xor(red[v], o);
        }
        if ((lane & 15) == 0) {
            #pragma unroll
            for (int v = 0; v < 8; ++v) atomicAdd(&sacc[m * 8 + v], red[v]);
        }
    }
    __syncthreads();
    if (tid < 64) atomicAdd(&sums[b * 64 + tid], sacc[tid]);
}

// ---------------- kernel B: sequential 8-module scan, one block per batch
__global__ __launch_bounds__(1024) void scan_coords(
    const float* __restrict__ coords,
    const float* __restrict__ ew_in, const float* __restrict__ sp_in,
    const float* __restrict__ sums, float* __restrict__ out)
{
    const int b   = blockIdx.x;
    const int tid = threadIdx.x;
    const int lane = tid & 63, wid = tid >> 6;
    __shared__ float redbuf[16 * 4];
    __shared__ float bcast[4];

    float cx[8], cy[8], cz[8];
    #pragma unroll
    for (int i = 0; i < 8; ++i) {
        int n = i * 1024 + tid;
        const float* cp = &coords[((size_t)b * NNODE + n) * 3];
        cx[i] = cp[0]; cy[i] = cp[1]; cz[i] = cp[2];
    }

    for (int m = 0; m < NMOD; ++m) {
        const float* ewp = &ew_in[((size_t)b * NMOD + m) * NNODE];
        const float* spp = &sp_in[((size_t)b * NMOD + m) * NNODE];
        float spl[8];
        float se = 0.f, sx = 0.f, sy = 0.f, sz = 0.f;
        #pragma unroll
        for (int i = 0; i < 8; ++i) {
            int n = i * 1024 + tid;
            float e = ewp[n];
            spl[i] = spp[n];
            se += e; sx += e * cx[i]; sy += e * cy[i]; sz += e * cz[i];
        }
        float vals[4] = {se, sx, sy, sz};
        #pragma unroll
        for (int v = 0; v < 4; ++v) {
            float x = vals[v];
            #pragma unroll
            for (int o = 32; o > 0; o >>= 1) x += __shfl_down(x, o);
            if (lane == 0) redbuf[wid * 4 + v] = x;
        }
        __syncthreads();
        if (tid < 4) {
            float s = 0.f;
            #pragma unroll
            for (int w = 0; w < 16; ++w) s += redbuf[w * 4 + tid];
            bcast[tid] = s;
        }
        __syncthreads();
        const float SE = bcast[0];
        const float AXc = bcast[1] / SE, AYc = bcast[2] / SE, AZc = bcast[3] / SE;

        const float* sm = &sums[((size_t)b * NMOD + m) * 8];
        float s  = fmaxf(sm[0], 1e-8f);
        float qw = sm[1] / s, qx = sm[2] / s, qy = sm[3] / s, qz = sm[4] / s;
        float qn = sqrtf(qw * qw + qx * qx + qy * qy + qz * qz);
        float qi = 1.f / fmaxf(qn, 1e-12f);
        qw *= qi; qx *= qi; qy *= qi; qz *= qi;
        float tgx = sm[5] / s, tgy = sm[6] / s, tgz = sm[7] / s;

        #pragma unroll
        for (int i = 0; i < 8; ++i) {
            float px = cx[i] - AXc, py = cy[i] - AYc, pz = cz[i] - AZc;
            float ux = qy * pz - qz * py;
            float uy = qz * px - qx * pz;
            float uz = qx * py - qy * px;
            float vx = qy * uz - qz * uy;
            float vy = qz * ux - qx * uz;
            float vz = qx * uy - qy * ux;
            float rx = px + 2.f * (qw * ux + vx);
            float ry = py + 2.f * (qw * uy + vy);
            float rz = pz + 2.f * (qw * uz + vz);
            float mx = rx + AXc + tgx, my = ry + AYc + tgy, mz = rz + AZc + tgz;
            float sp = spl[i];
            cx[i] += sp * (mx - cx[i]);
            cy[i] += sp * (my - cy[i]);
            cz[i] += sp * (mz - cz[i]);
        }
        __syncthreads();
    }

    #pragma unroll
    for (int i = 0; i < 8; ++i) {
        int n = i * 1024 + tid;
        float* op = &out[((size_t)b * NNODE + n) * 3];
        op[0] = cx[i]; op[1] = cy[i]; op[2] = cz[i];
    }
}

extern "C" void kernel_launch(void* const* d_in, const int* in_sizes, int n_in,
                              void* d_out, int out_size, void* d_ws, size_t ws_size,
                              hipStream_t stream) {
    const float* feats  = (const float*)d_in[0];
    const float* coords = (const float*)d_in[1];
    const float* W      = (const float*)d_in[2];
    const float* bias   = (const float*)d_in[3];
    float* out = (float*)d_out;

    char* ws = (char*)d_ws;
    unsigned short* Bpk = (unsigned short*)(ws);                  // 256 KB
    float* ew   = (float*)(ws + 262144);                          // 2 MB
    float* sp   = (float*)(ws + 262144 + 2097152);                // 2 MB
    float* sums = (float*)(ws + 262144 + 2 * 2097152);            // 2 KB

    hipMemsetAsync(sums, 0, (size_t)BATCH * NMOD * 8 * sizeof(float), stream);
    pack_b<<<64, 256, 0, stream>>>(W, Bpk);
    gemm_mfma<<<(BATCH * NNODE) / 64, 256, 0, stream>>>(feats, Bpk, bias, ew, sp, sums);
    scan_coords<<<BATCH, 1024, 0, stream>>>(coords, ew, sp, sums, out);
}

// Round 3
// 110.609 us; speedup vs baseline: 2.2039x; 1.1813x over previous
//
#include <hip/hip_runtime.h>
#include <hip/hip_bf16.h>
#include <math.h>

#define D_MODEL 1024
#define NMOD 8
#define BATCH 8
#define NNODE 8192
#define PI_F 3.14159265358979323846f
#define MAXT 3.0f

typedef short bf16x8 __attribute__((ext_vector_type(8)));
typedef float f32x4 __attribute__((ext_vector_type(4)));

__device__ inline unsigned short f2bf(float x) {
    __hip_bfloat16 h = __float2bfloat16(x);   // RNE, compiler can pack to v_cvt_pk_bf16_f32
    return __builtin_bit_cast(unsigned short, h);
}
__device__ inline float bf2f(unsigned short h) {
    unsigned u = ((unsigned)h) << 16;
    return __builtin_bit_cast(float, u);
}

// ---------------- kernel 0: pack W (bf16, hi only) into MFMA B-fragment lane order
// Entry e = (ks*4 + g)*64 + lane, 8 ushorts each.
// Lane l, reg r holds B[k = ks*32 + (l>>4)*8 + r][col j = g*16 + (l&15)] = W[j][k]
__global__ void pack_b(const float* __restrict__ W, unsigned short* __restrict__ Bpk) {
    int t = blockIdx.x * 256 + threadIdx.x;   // 8192 total
    int l  = t & 63;
    int g  = (t >> 6) & 3;
    int ks = t >> 8;
    int j  = g * 16 + (l & 15);
    int k0 = ks * 32 + ((l >> 4) * 8);
    const float* wp = &W[(size_t)j * D_MODEL + k0];
    bf16x8 pack;
    #pragma unroll
    for (int r = 0; r < 8; ++r) pack[r] = (short)f2bf(wp[r]);
    *reinterpret_cast<bf16x8*>(Bpk + (size_t)t * 8) = pack;
}

// ---------------- kernel A: MFMA GEMM (A split hi/lo, B bf16) + activations + group sums
__global__ __launch_bounds__(256, 4) void gemm_mfma(
    const float* __restrict__ feats, const unsigned short* __restrict__ Bpk,
    const float* __restrict__ bias,
    float* __restrict__ ew_out, float* __restrict__ sp_out,
    float* __restrict__ sums)
{
    __shared__ float pbuf[4][16][68];   // per-wave param transpose buffer
    __shared__ float sacc[64];          // per-block module sums [m][v]

    const int tid  = threadIdx.x;
    const int lane = tid & 63;
    const int wv   = tid >> 6;

    if (tid < 64) sacc[tid] = 0.f;
    __syncthreads();

    const int mt    = blockIdx.x * 4 + wv;   // m-tile (16 nodes)
    const int mbase = mt * 16;
    const float* arow = feats + (size_t)(mbase + (lane & 15)) * D_MODEL + ((lane >> 4) * 8);
    const bf16x8* bp = reinterpret_cast<const bf16x8*>(Bpk);

    f32x4 acc[4];
    #pragma unroll
    for (int g = 0; g < 4; ++g) acc[g] = (f32x4){0.f, 0.f, 0.f, 0.f};

    #pragma unroll 2
    for (int ks = 0; ks < 32; ++ks) {
        const float4 fa = *reinterpret_cast<const float4*>(arow + ks * 32);
        const float4 fb = *reinterpret_cast<const float4*>(arow + ks * 32 + 4);
        float f[8] = {fa.x, fa.y, fa.z, fa.w, fb.x, fb.y, fb.z, fb.w};
        bf16x8 ahi, alo;
        #pragma unroll
        for (int i = 0; i < 8; ++i) {
            unsigned short h = f2bf(f[i]);
            ahi[i] = (short)h;
            alo[i] = (short)f2bf(f[i] - bf2f(h));
        }
        #pragma unroll
        for (int g = 0; g < 4; ++g) {
            bf16x8 bh = bp[(ks * 4 + g) * 64 + lane];
            acc[g] = __builtin_amdgcn_mfma_f32_16x16x32_bf16(ahi, bh, acc[g], 0, 0, 0);
            acc[g] = __builtin_amdgcn_mfma_f32_16x16x32_bf16(alo, bh, acc[g], 0, 0, 0);
        }
    }

    // params -> per-wave LDS (add bias). D: row=(lane>>4)*4+reg, col=g*16+(lane&15)
    #pragma unroll
    for (int g = 0; g < 4; ++g) {
        float bj = bias[g * 16 + (lane & 15)];
        #pragma unroll
        for (int r = 0; r < 4; ++r)
            pbuf[wv][(lane >> 4) * 4 + r][g * 16 + (lane & 15)] = acc[g][r] + bj;
    }
    // same-wave ds_write -> ds_read: compiler inserts lgkmcnt wait; no barrier needed.

    const int b    = mbase >> 13;     // / 8192
    const int nInB = mbase & 8191;

    #pragma unroll
    for (int h = 0; h < 2; ++h) {
        const int node = lane & 15;
        const int m    = (lane >> 4) + 4 * h;
        const float* pa = &pbuf[wv][node][m * 8];
        float al = pa[0], sl = pa[1];
        float ax = pa[2], ay = pa[3], az = pa[4];
        float tx = pa[5], ty = pa[6], tz = pa[7];

        float ew = expf(al);
        float sp = 1.f / (1.f + expf(-sl));

        float n0  = sqrtf(ax * ax + ay * ay + az * az);
        float inv = 1.f / fmaxf(n0, 1e-12f);
        float ang = tanhf(n0) * PI_F;
        float hf  = 0.5f * ang;
        float shoa = (ang < 1e-6f) ? (0.5f - ang * ang * (1.f / 48.f))
                                   : (sinf(hf) / ang);
        float qw = cosf(hf);
        float fac = inv * ang * shoa;
        float qx = ax * fac, qy = ay * fac, qz = az * fac;

        float ttx = tanhf(tx) * MAXT, tty = tanhf(ty) * MAXT, ttz = tanhf(tz) * MAXT;

        size_t base = ((size_t)(b * NMOD + m)) * NNODE + nInB + node;
        ew_out[base] = ew;
        sp_out[base] = sp;

        float red[8];
        red[0] = sp;
        red[1] = sp * qw; red[2] = sp * qx; red[3] = sp * qy; red[4] = sp * qz;
        red[5] = sp * ttx; red[6] = sp * tty; red[7] = sp * ttz;
        #pragma unroll
        for (int v = 0; v < 8; ++v) {
            #pragma unroll
            for (int o = 1; o < 16; o <<= 1) red[v] += __shfl_xor(red[v], o);
        }
        if ((lane & 15) == 0) {
            #pragma unroll
            for (int v = 0; v < 8; ++v) atomicAdd(&sacc[m * 8 + v], red[v]);
        }
    }
    __syncthreads();
    if (tid < 64) atomicAdd(&sums[b * 64 + tid], sacc[tid]);
}

// ---------------- kernel B: sequential 8-module scan, one block per batch
__global__ __launch_bounds__(1024) void scan_coords(
    const float* __restrict__ coords,
    const float* __restrict__ ew_in, const float* __restrict__ sp_in,
    const float* __restrict__ sums, float* __restrict__ out)
{
    const int b   = blockIdx.x;
    const int tid = threadIdx.x;
    const int lane = tid & 63, wid = tid >> 6;
    __shared__ float redbuf[64];    // 16 waves x 4 vals
    __shared__ float bcast[4];

    const int n0 = tid * 8;         // 8 contiguous nodes per thread

    float cx[8], cy[8], cz[8];
    {
        float c[24];
        const float4* cp4 = reinterpret_cast<const float4*>(
            &coords[((size_t)b * NNODE + n0) * 3]);
        #pragma unroll
        for (int q = 0; q < 6; ++q) {
            float4 v = cp4[q];
            c[q * 4 + 0] = v.x; c[q * 4 + 1] = v.y;
            c[q * 4 + 2] = v.z; c[q * 4 + 3] = v.w;
        }
        #pragma unroll
        for (int i = 0; i < 8; ++i) { cx[i] = c[3*i]; cy[i] = c[3*i+1]; cz[i] = c[3*i+2]; }
    }

    for (int m = 0; m < NMOD; ++m) {
        const float* ewp = &ew_in[((size_t)b * NMOD + m) * NNODE];
        const float* spp = &sp_in[((size_t)b * NMOD + m) * NNODE];
        float ev[8], spl[8];
        {
            float4 e0 = *reinterpret_cast<const float4*>(&ewp[n0]);
            float4 e1 = *reinterpret_cast<const float4*>(&ewp[n0 + 4]);
            float4 s0 = *reinterpret_cast<const float4*>(&spp[n0]);
            float4 s1 = *reinterpret_cast<const float4*>(&spp[n0 + 4]);
            ev[0]=e0.x; ev[1]=e0.y; ev[2]=e0.z; ev[3]=e0.w;
            ev[4]=e1.x; ev[5]=e1.y; ev[6]=e1.z; ev[7]=e1.w;
            spl[0]=s0.x; spl[1]=s0.y; spl[2]=s0.z; spl[3]=s0.w;
            spl[4]=s1.x; spl[5]=s1.y; spl[6]=s1.z; spl[7]=s1.w;
        }
        float se = 0.f, sx = 0.f, sy = 0.f, sz = 0.f;
        #pragma unroll
        for (int i = 0; i < 8; ++i) {
            se += ev[i]; sx += ev[i] * cx[i]; sy += ev[i] * cy[i]; sz += ev[i] * cz[i];
        }
        float vals[4] = {se, sx, sy, sz};
        #pragma unroll
        for (int v = 0; v < 4; ++v) {
            float x = vals[v];
            #pragma unroll
            for (int o = 32; o > 0; o >>= 1) x += __shfl_down(x, o);
            if (lane == 0) redbuf[wid * 4 + v] = x;
        }
        __syncthreads();
        if (wid == 0) {
            float x = redbuf[lane];              // lane = w*4+v
            x += __shfl_down(x, 32);
            x += __shfl_down(x, 16);
            x += __shfl_down(x, 8);
            x += __shfl_down(x, 4);
            if (lane < 4) bcast[lane] = x;
        }
        __syncthreads();
        const float SE = bcast[0];
        const float AXc = bcast[1] / SE, AYc = bcast[2] / SE, AZc = bcast[3] / SE;

        const float* sm = &sums[((size_t)b * NMOD + m) * 8];
        float s  = fmaxf(sm[0], 1e-8f);
        float qw = sm[1] / s, qx = sm[2] / s, qy = sm[3] / s, qz = sm[4] / s;
        float qn = sqrtf(qw * qw + qx * qx + qy * qy + qz * qz);
        float qi = 1.f / fmaxf(qn, 1e-12f);
        qw *= qi; qx *= qi; qy *= qi; qz *= qi;
        float tgx = sm[5] / s, tgy = sm[6] / s, tgz = sm[7] / s;

        #pragma unroll
        for (int i = 0; i < 8; ++i) {
            float px = cx[i] - AXc, py = cy[i] - AYc, pz = cz[i] - AZc;
            float ux = qy * pz - qz * py;
            float uy = qz * px - qx * pz;
            float uz = qx * py - qy * px;
            float vx = qy * uz - qz * uy;
            float vy = qz * ux - qx * uz;
            float vz = qx * uy - qy * ux;
            float rx = px + 2.f * (qw * ux + vx);
            float ry = py + 2.f * (qw * uy + vy);
            float rz = pz + 2.f * (qw * uz + vz);
            float mx = rx + AXc + tgx, my = ry + AYc + tgy, mz = rz + AZc + tgz;
            float sp = spl[i];
            cx[i] += sp * (mx - cx[i]);
            cy[i] += sp * (my - cy[i]);
            cz[i] += sp * (mz - cz[i]);
        }
        __syncthreads();
    }

    {
        float c[24];
        #pragma unroll
        for (int i = 0; i < 8; ++i) { c[3*i] = cx[i]; c[3*i+1] = cy[i]; c[3*i+2] = cz[i]; }
        float4* op4 = reinterpret_cast<float4*>(&out[((size_t)b * NNODE + n0) * 3]);
        #pragma unroll
        for (int q = 0; q < 6; ++q)
            op4[q] = make_float4(c[q*4+0], c[q*4+1], c[q*4+2], c[q*4+3]);
    }
}

extern "C" void kernel_launch(void* const* d_in, const int* in_sizes, int n_in,
                              void* d_out, int out_size, void* d_ws, size_t ws_size,
                              hipStream_t stream) {
    const float* feats  = (const float*)d_in[0];
    const float* coords = (const float*)d_in[1];
    const float* W      = (const float*)d_in[2];
    const float* bias   = (const float*)d_in[3];
    float* out = (float*)d_out;

    char* ws = (char*)d_ws;
    unsigned short* Bpk = (unsigned short*)(ws);                  // 128 KB
    float* ew   = (float*)(ws + 262144);                          // 2 MB
    float* sp   = (float*)(ws + 262144 + 2097152);                // 2 MB
    float* sums = (float*)(ws + 262144 + 2 * 2097152);            // 2 KB

    hipMemsetAsync(sums, 0, (size_t)BATCH * NMOD * 8 * sizeof(float), stream);
    pack_b<<<32, 256, 0, stream>>>(W, Bpk);
    gemm_mfma<<<(BATCH * NNODE) / 64, 256, 0, stream>>>(feats, Bpk, bias, ew, sp, sums);
    scan_coords<<<BATCH, 1024, 0, stream>>>(coords, ew, sp, sums, out);
}

// Round 4
// 104.582 us; speedup vs baseline: 2.3309x; 1.0576x over previous
//
#include <hip/hip_runtime.h>
#include <hip/hip_bf16.h>
#include <hip/hip_fp16.h>
#include <math.h>

#define D_MODEL 1024
#define NMOD 8
#define BATCH 8
#define NNODE 8192
#define PI_F 3.14159265358979323846f
#define MAXT 3.0f

typedef short bf16x8 __attribute__((ext_vector_type(8)));
typedef float f32x4 __attribute__((ext_vector_type(4)));

__device__ inline unsigned short f2bf(float x) {
    __hip_bfloat16 h = __float2bfloat16(x);   // RNE
    return __builtin_bit_cast(unsigned short, h);
}
__device__ inline float h2f(unsigned short u) {
    __half h = __builtin_bit_cast(__half, u);
    return __half2float(h);
}
__device__ inline unsigned short f2h(float x) {
    __half h = __float2half(x);
    return __builtin_bit_cast(unsigned short, h);
}

// ---------------- kernel 0: pack W (bf16) into MFMA B-fragment lane order
// Entry e = (ks*4 + g)*64 + lane, 8 ushorts each.
// Lane l, reg r holds B[k = ks*32 + (l>>4)*8 + r][col j = g*16 + (l&15)] = W[j][k]
__global__ void pack_b(const float* __restrict__ W, unsigned short* __restrict__ Bpk) {
    int t = blockIdx.x * 256 + threadIdx.x;   // 8192 total
    int l  = t & 63;
    int g  = (t >> 6) & 3;
    int ks = t >> 8;
    int j  = g * 16 + (l & 15);
    int k0 = ks * 32 + ((l >> 4) * 8);
    const float* wp = &W[(size_t)j * D_MODEL + k0];
    bf16x8 pack;
    #pragma unroll
    for (int r = 0; r < 8; ++r) pack[r] = (short)f2bf(wp[r]);
    *reinterpret_cast<bf16x8*>(Bpk + (size_t)t * 8) = pack;
}

// ---------------- kernel A: bf16 MFMA GEMM + activations + group sums
__global__ __launch_bounds__(256, 4) void gemm_mfma(
    const float* __restrict__ feats, const unsigned short* __restrict__ Bpk,
    const float* __restrict__ bias,
    unsigned int* __restrict__ esp_out,    // packed {fp16 sp | fp16 ew}
    float* __restrict__ sums)
{
    __shared__ float pbuf[4][16][68];   // per-wave param transpose buffer
    __shared__ float sacc[64];          // per-block module sums [m][v]

    const int tid  = threadIdx.x;
    const int lane = tid & 63;
    const int wv   = tid >> 6;

    if (tid < 64) sacc[tid] = 0.f;
    __syncthreads();

    const int mt    = blockIdx.x * 4 + wv;   // m-tile (16 nodes)
    const int mbase = mt * 16;
    const float* arow = feats + (size_t)(mbase + (lane & 15)) * D_MODEL + ((lane >> 4) * 8);
    const bf16x8* bp = reinterpret_cast<const bf16x8*>(Bpk);

    f32x4 acc[4];
    #pragma unroll
    for (int g = 0; g < 4; ++g) acc[g] = (f32x4){0.f, 0.f, 0.f, 0.f};

    #pragma unroll 2
    for (int ks = 0; ks < 32; ++ks) {
        const float4 fa = *reinterpret_cast<const float4*>(arow + ks * 32);
        const float4 fb = *reinterpret_cast<const float4*>(arow + ks * 32 + 4);
        float f[8] = {fa.x, fa.y, fa.z, fa.w, fb.x, fb.y, fb.z, fb.w};
        bf16x8 a;
        #pragma unroll
        for (int i = 0; i < 8; ++i) a[i] = (short)f2bf(f[i]);
        #pragma unroll
        for (int g = 0; g < 4; ++g) {
            bf16x8 bh = bp[(ks * 4 + g) * 64 + lane];
            acc[g] = __builtin_amdgcn_mfma_f32_16x16x32_bf16(a, bh, acc[g], 0, 0, 0);
        }
    }

    // params -> per-wave LDS (add bias). D: row=(lane>>4)*4+reg, col=g*16+(lane&15)
    #pragma unroll
    for (int g = 0; g < 4; ++g) {
        float bj = bias[g * 16 + (lane & 15)];
        #pragma unroll
        for (int r = 0; r < 4; ++r)
            pbuf[wv][(lane >> 4) * 4 + r][g * 16 + (lane & 15)] = acc[g][r] + bj;
    }
    // same-wave ds_write -> ds_read: compiler inserts lgkmcnt wait; no barrier needed.

    const int b    = mbase >> 13;     // / 8192
    const int nInB = mbase & 8191;

    #pragma unroll
    for (int h = 0; h < 2; ++h) {
        const int node = lane & 15;
        const int m    = (lane >> 4) + 4 * h;
        const float* pa = &pbuf[wv][node][m * 8];
        float al = pa[0], sl = pa[1];
        float ax = pa[2], ay = pa[3], az = pa[4];
        float tx = pa[5], ty = pa[6], tz = pa[7];

        float ew = expf(al);
        float sp = 1.f / (1.f + expf(-sl));

        float n0  = sqrtf(ax * ax + ay * ay + az * az);
        float inv = 1.f / fmaxf(n0, 1e-12f);
        float ang = tanhf(n0) * PI_F;
        float hf  = 0.5f * ang;
        float shoa = (ang < 1e-6f) ? (0.5f - ang * ang * (1.f / 48.f))
                                   : (sinf(hf) / ang);
        float qw = cosf(hf);
        float fac = inv * ang * shoa;
        float qx = ax * fac, qy = ay * fac, qz = az * fac;

        float ttx = tanhf(tx) * MAXT, tty = tanhf(ty) * MAXT, ttz = tanhf(tz) * MAXT;

        size_t base = ((size_t)(b * NMOD + m)) * NNODE + nInB + node;
        esp_out[base] = ((unsigned)f2h(sp) << 16) | (unsigned)f2h(ew);

        float red[8];
        red[0] = sp;
        red[1] = sp * qw; red[2] = sp * qx; red[3] = sp * qy; red[4] = sp * qz;
        red[5] = sp * ttx; red[6] = sp * tty; red[7] = sp * ttz;
        #pragma unroll
        for (int v = 0; v < 8; ++v) {
            #pragma unroll
            for (int o = 1; o < 16; o <<= 1) red[v] += __shfl_xor(red[v], o);
        }
        if ((lane & 15) == 0) {
            #pragma unroll
            for (int v = 0; v < 8; ++v) atomicAdd(&sacc[m * 8 + v], red[v]);
        }
    }
    __syncthreads();
    if (tid < 64) atomicAdd(&sums[b * 64 + tid], sacc[tid]);
}

// ---------------- kernel B: sequential 8-module scan, one block per batch
__global__ __launch_bounds__(1024) void scan_coords(
    const float* __restrict__ coords,
    const unsigned int* __restrict__ esp_in,
    const float* __restrict__ sums, float* __restrict__ out)
{
    const int b   = blockIdx.x;
    const int tid = threadIdx.x;
    const int lane = tid & 63, wid = tid >> 6;
    __shared__ float redbuf[64];    // 16 waves x 4 vals
    __shared__ float bcast[4];

    const int n0 = tid * 8;         // 8 contiguous nodes per thread

    float cx[8], cy[8], cz[8];
    {
        float c[24];
        const float4* cp4 = reinterpret_cast<const float4*>(
            &coords[((size_t)b * NNODE + n0) * 3]);
        #pragma unroll
        for (int q = 0; q < 6; ++q) {
            float4 v = cp4[q];
            c[q * 4 + 0] = v.x; c[q * 4 + 1] = v.y;
            c[q * 4 + 2] = v.z; c[q * 4 + 3] = v.w;
        }
        #pragma unroll
        for (int i = 0; i < 8; ++i) { cx[i] = c[3*i]; cy[i] = c[3*i+1]; cz[i] = c[3*i+2]; }
    }

    const uint4* esp4 = reinterpret_cast<const uint4*>(
        &esp_in[(size_t)b * NMOD * NNODE]);
    // per module: 2 uint4 at (m*NNODE + n0)/4
    uint4 cur0 = esp4[(0 * NNODE + n0) >> 2];
    uint4 cur1 = esp4[((0 * NNODE + n0) >> 2) + 1];

    for (int m = 0; m < NMOD; ++m) {
        // prefetch next module's packed ew/sp (hides L3/HBM latency under this module)
        const int mn = (m + 1 < NMOD) ? m + 1 : m;
        uint4 nxt0 = esp4[(mn * NNODE + n0) >> 2];
        uint4 nxt1 = esp4[((mn * NNODE + n0) >> 2) + 1];

        unsigned pk[8] = {cur0.x, cur0.y, cur0.z, cur0.w, cur1.x, cur1.y, cur1.z, cur1.w};
        float ev[8], spl[8];
        #pragma unroll
        for (int i = 0; i < 8; ++i) {
            ev[i]  = h2f((unsigned short)(pk[i] & 0xFFFFu));
            spl[i] = h2f((unsigned short)(pk[i] >> 16));
        }

        float se = 0.f, sx = 0.f, sy = 0.f, sz = 0.f;
        #pragma unroll
        for (int i = 0; i < 8; ++i) {
            se += ev[i]; sx += ev[i] * cx[i]; sy += ev[i] * cy[i]; sz += ev[i] * cz[i];
        }
        float vals[4] = {se, sx, sy, sz};
        #pragma unroll
        for (int v = 0; v < 4; ++v) {
            float x = vals[v];
            #pragma unroll
            for (int o = 32; o > 0; o >>= 1) x += __shfl_down(x, o);
            if (lane == 0) redbuf[wid * 4 + v] = x;
        }
        __syncthreads();
        if (wid == 0) {
            float x = redbuf[lane];              // lane = w*4+v
            x += __shfl_down(x, 32);
            x += __shfl_down(x, 16);
            x += __shfl_down(x, 8);
            x += __shfl_down(x, 4);
            if (lane < 4) bcast[lane] = x;
        }
        __syncthreads();
        const float SE = bcast[0];
        const float AXc = bcast[1] / SE, AYc = bcast[2] / SE, AZc = bcast[3] / SE;

        const float* sm = &sums[((size_t)b * NMOD + m) * 8];
        float s  = fmaxf(sm[0], 1e-8f);
        float qw = sm[1] / s, qx = sm[2] / s, qy = sm[3] / s, qz = sm[4] / s;
        float qn = sqrtf(qw * qw + qx * qx + qy * qy + qz * qz);
        float qi = 1.f / fmaxf(qn, 1e-12f);
        qw *= qi; qx *= qi; qy *= qi; qz *= qi;
        float tgx = sm[5] / s, tgy = sm[6] / s, tgz = sm[7] / s;

        #pragma unroll
        for (int i = 0; i < 8; ++i) {
            float px = cx[i] - AXc, py = cy[i] - AYc, pz = cz[i] - AZc;
            float ux = qy * pz - qz * py;
            float uy = qz * px - qx * pz;
            float uz = qx * py - qy * px;
            float vx = qy * uz - qz * uy;
            float vy = qz * ux - qx * uz;
            float vz = qx * uy - qy * ux;
            float rx = px + 2.f * (qw * ux + vx);
            float ry = py + 2.f * (qw * uy + vy);
            float rz = pz + 2.f * (qw * uz + vz);
            float mx = rx + AXc + tgx, my = ry + AYc + tgy, mz = rz + AZc + tgz;
            float sp = spl[i];
            cx[i] += sp * (mx - cx[i]);
            cy[i] += sp * (my - cy[i]);
            cz[i] += sp * (mz - cz[i]);
        }
        cur0 = nxt0; cur1 = nxt1;
        __syncthreads();
    }

    {
        float c[24];
        #pragma unroll
        for (int i = 0; i < 8; ++i) { c[3*i] = cx[i]; c[3*i+1] = cy[i]; c[3*i+2] = cz[i]; }
        float4* op4 = reinterpret_cast<float4*>(&out[((size_t)b * NNODE + n0) * 3]);
        #pragma unroll
        for (int q = 0; q < 6; ++q)
            op4[q] = make_float4(c[q*4+0], c[q*4+1], c[q*4+2], c[q*4+3]);
    }
}

extern "C" void kernel_launch(void* const* d_in, const int* in_sizes, int n_in,
                              void* d_out, int out_size, void* d_ws, size_t ws_size,
                              hipStream_t stream) {
    const float* feats  = (const float*)d_in[0];
    const float* coords = (const float*)d_in[1];
    const float* W      = (const float*)d_in[2];
    const float* bias   = (const float*)d_in[3];
    float* out = (float*)d_out;

    char* ws = (char*)d_ws;
    unsigned short* Bpk = (unsigned short*)(ws);                  // 128 KB (256 KB reserved)
    unsigned int* esp   = (unsigned int*)(ws + 262144);           // 2 MB packed {sp|ew}
    float* sums         = (float*)(ws + 262144 + 2097152);        // 2 KB

    hipMemsetAsync(sums, 0, (size_t)BATCH * NMOD * 8 * sizeof(float), stream);
    pack_b<<<32, 256, 0, stream>>>(W, Bpk);
    gemm_mfma<<<(BATCH * NNODE) / 64, 256, 0, stream>>>(feats, Bpk, bias, esp, sums);
    scan_coords<<<BATCH, 1024, 0, stream>>>(coords, esp, sums, out);
}

// Round 5
// 99.075 us; speedup vs baseline: 2.4605x; 1.0556x over previous
//
#include <hip/hip_runtime.h>
#include <hip/hip_bf16.h>
#include <hip/hip_fp16.h>
#include <math.h>

#define D_MODEL 1024
#define NMOD 8
#define BATCH 8
#define NNODE 8192
#define PI_F 3.14159265358979323846f
#define MAXT 3.0f

typedef short bf16x8 __attribute__((ext_vector_type(8)));
typedef float f32x4 __attribute__((ext_vector_type(4)));

__device__ inline unsigned short f2bf(float x) {
    __hip_bfloat16 h = __float2bfloat16(x);   // RNE
    return __builtin_bit_cast(unsigned short, h);
}
__device__ inline float h2f(unsigned short u) {
    __half h = __builtin_bit_cast(__half, u);
    return __half2float(h);
}
__device__ inline unsigned short f2h(float x) {
    __half h = __float2half(x);
    return __builtin_bit_cast(unsigned short, h);
}

// ---------------- kernel 0: pack W (bf16) into MFMA B-fragment lane order
// Entry e = (ks*4 + g)*64 + lane, 8 ushorts each.
// Lane l, reg r holds B[k = ks*32 + (l>>4)*8 + r][col j = g*16 + (l&15)] = W[j][k]
__global__ void pack_b(const float* __restrict__ W, unsigned short* __restrict__ Bpk) {
    int t = blockIdx.x * 256 + threadIdx.x;   // 8192 total
    int l  = t & 63;
    int g  = (t >> 6) & 3;
    int ks = t >> 8;
    int j  = g * 16 + (l & 15);
    int k0 = ks * 32 + ((l >> 4) * 8);
    const float* wp = &W[(size_t)j * D_MODEL + k0];
    bf16x8 pack;
    #pragma unroll
    for (int r = 0; r < 8; ++r) pack[r] = (short)f2bf(wp[r]);
    *reinterpret_cast<bf16x8*>(Bpk + (size_t)t * 8) = pack;
}

__device__ __forceinline__ void loadg(float4 (&dst)[8], const float* arow, int g4) {
    #pragma unroll
    for (int i = 0; i < 4; ++i) {
        dst[2 * i]     = *reinterpret_cast<const float4*>(arow + (g4 * 4 + i) * 32);
        dst[2 * i + 1] = *reinterpret_cast<const float4*>(arow + (g4 * 4 + i) * 32 + 4);
    }
}

__device__ __forceinline__ void compg(const float4 (&src)[8], int g4,
                                      const unsigned short* Blds, int lane,
                                      f32x4 (&acc)[4]) {
    #pragma unroll
    for (int i = 0; i < 4; ++i) {
        float f[8] = {src[2*i].x, src[2*i].y, src[2*i].z, src[2*i].w,
                      src[2*i+1].x, src[2*i+1].y, src[2*i+1].z, src[2*i+1].w};
        bf16x8 a;
        #pragma unroll
        for (int j = 0; j < 8; ++j) a[j] = (short)f2bf(f[j]);
        const int ks = g4 * 4 + i;
        #pragma unroll
        for (int g = 0; g < 4; ++g) {
            bf16x8 bh = *reinterpret_cast<const bf16x8*>(
                Blds + ((size_t)((ks * 4 + g) * 64 + lane)) * 8);
            acc[g] = __builtin_amdgcn_mfma_f32_16x16x32_bf16(a, bh, acc[g], 0, 0, 0);
        }
    }
}

// ---------------- kernel A: bf16 MFMA GEMM, whole W in LDS, 1 block/CU
__global__ __launch_bounds__(1024) void gemm_mfma(
    const float* __restrict__ feats, const unsigned short* __restrict__ Bpk,
    const float* __restrict__ bias,
    unsigned int* __restrict__ esp_out,    // packed {fp16 sp | fp16 ew}
    float* __restrict__ sums)
{
    __shared__ __align__(16) unsigned char smem[131072];   // B (main) / pbuf+sacc (epilogue)

    const int tid  = threadIdx.x;
    const int lane = tid & 63;
    const int wv   = tid >> 6;          // 0..15

    // ---- stage all of packed W (128 KB) into LDS, linear layout
    {
        const char* gsrc = (const char*)Bpk;
        #pragma unroll
        for (int r = 0; r < 8; ++r) {
            const int off = r * 16384 + wv * 1024;
            __builtin_amdgcn_global_load_lds(
                (const __attribute__((address_space(1))) unsigned int*)(gsrc + off + lane * 16),
                (__attribute__((address_space(3))) unsigned int*)(smem + off),
                16, 0, 0);
        }
    }

    const int mt    = blockIdx.x * 16 + wv;   // m-tile (16 nodes)
    const int mbase = mt * 16;
    const float* arow = feats + (size_t)(mbase + (lane & 15)) * D_MODEL + ((lane >> 4) * 8);
    const unsigned short* Blds = (const unsigned short*)smem;

    f32x4 acc[4];
    #pragma unroll
    for (int g = 0; g < 4; ++g) acc[g] = (f32x4){0.f, 0.f, 0.f, 0.f};

    float4 A0[8], A1[8];
    loadg(A0, arow, 0);        // issued before barrier; drains with the gll vmcnt(0)
    loadg(A1, arow, 1);
    __syncthreads();           // B staged

    #pragma unroll
    for (int g4 = 0; g4 < 8; g4 += 2) {
        compg(A0, g4, Blds, lane, acc);
        if (g4 + 2 < 8) loadg(A0, arow, g4 + 2);
        compg(A1, g4 + 1, Blds, lane, acc);
        if (g4 + 3 < 8) loadg(A1, arow, g4 + 3);
    }

    // ---- epilogue: alias dead B region as pbuf (16 waves x 16 x 68 f32) + sacc
    __syncthreads();                                   // all waves done reading B
    float* pbuf = reinterpret_cast<float*>(smem) + (size_t)wv * (16 * 68);
    float* sacc = reinterpret_cast<float*>(smem + 16 * 16 * 68 * 4);   // offset 69632
    if (tid < 64) sacc[tid] = 0.f;

    // params -> per-wave LDS (add bias). D: row=(lane>>4)*4+reg, col=g*16+(lane&15)
    #pragma unroll
    for (int g = 0; g < 4; ++g) {
        float bj = bias[g * 16 + (lane & 15)];
        #pragma unroll
        for (int r = 0; r < 4; ++r)
            pbuf[((lane >> 4) * 4 + r) * 68 + g * 16 + (lane & 15)] = acc[g][r] + bj;
    }
    __syncthreads();                                   // sacc zero visible

    const int b    = mbase >> 13;     // / 8192 (uniform per block)
    const int nInB = mbase & 8191;

    #pragma unroll
    for (int h = 0; h < 2; ++h) {
        const int node = lane & 15;
        const int m    = (lane >> 4) + 4 * h;
        const float* pa = &pbuf[node * 68 + m * 8];
        float al = pa[0], sl = pa[1];
        float ax = pa[2], ay = pa[3], az = pa[4];
        float tx = pa[5], ty = pa[6], tz = pa[7];

        float ew = expf(al);
        float sp = 1.f / (1.f + expf(-sl));

        float n0  = sqrtf(ax * ax + ay * ay + az * az);
        float inv = 1.f / fmaxf(n0, 1e-12f);
        float ang = tanhf(n0) * PI_F;
        float hf  = 0.5f * ang;
        float shoa = (ang < 1e-6f) ? (0.5f - ang * ang * (1.f / 48.f))
                                   : (sinf(hf) / ang);
        float qw = cosf(hf);
        float fac = inv * ang * shoa;
        float qx = ax * fac, qy = ay * fac, qz = az * fac;

        float ttx = tanhf(tx) * MAXT, tty = tanhf(ty) * MAXT, ttz = tanhf(tz) * MAXT;

        size_t base = ((size_t)(b * NMOD + m)) * NNODE + nInB + node;
        esp_out[base] = ((unsigned)f2h(sp) << 16) | (unsigned)f2h(ew);

        float red[8];
        red[0] = sp;
        red[1] = sp * qw; red[2] = sp * qx; red[3] = sp * qy; red[4] = sp * qz;
        red[5] = sp * ttx; red[6] = sp * tty; red[7] = sp * ttz;
        #pragma unroll
        for (int v = 0; v < 8; ++v) {
            #pragma unroll
            for (int o = 1; o < 16; o <<= 1) red[v] += __shfl_xor(red[v], o);
        }
        if ((lane & 15) == 0) {
            #pragma unroll
            for (int v = 0; v < 8; ++v) atomicAdd(&sacc[m * 8 + v], red[v]);
        }
    }
    __syncthreads();
    if (tid < 64) atomicAdd(&sums[b * 64 + tid], sacc[tid]);
}

// ---------------- kernel B: sequential 8-module scan, one block per batch
__global__ __launch_bounds__(1024) void scan_coords(
    const float* __restrict__ coords,
    const unsigned int* __restrict__ esp_in,
    const float* __restrict__ sums, float* __restrict__ out)
{
    const int b   = blockIdx.x;
    const int tid = threadIdx.x;
    const int lane = tid & 63, wid = tid >> 6;
    __shared__ float redbuf[64];    // 16 waves x 4 vals
    __shared__ float bcast[4];

    const int n0 = tid * 8;         // 8 contiguous nodes per thread

    float cx[8], cy[8], cz[8];
    {
        float c[24];
        const float4* cp4 = reinterpret_cast<const float4*>(
            &coords[((size_t)b * NNODE + n0) * 3]);
        #pragma unroll
        for (int q = 0; q < 6; ++q) {
            float4 v = cp4[q];
            c[q * 4 + 0] = v.x; c[q * 4 + 1] = v.y;
            c[q * 4 + 2] = v.z; c[q * 4 + 3] = v.w;
        }
        #pragma unroll
        for (int i = 0; i < 8; ++i) { cx[i] = c[3*i]; cy[i] = c[3*i+1]; cz[i] = c[3*i+2]; }
    }

    const uint4* esp4 = reinterpret_cast<const uint4*>(
        &esp_in[(size_t)b * NMOD * NNODE]);
    uint4 cur0 = esp4[(0 * NNODE + n0) >> 2];
    uint4 cur1 = esp4[((0 * NNODE + n0) >> 2) + 1];

    for (int m = 0; m < NMOD; ++m) {
        const int mn = (m + 1 < NMOD) ? m + 1 : m;
        uint4 nxt0 = esp4[(mn * NNODE + n0) >> 2];
        uint4 nxt1 = esp4[((mn * NNODE + n0) >> 2) + 1];

        unsigned pk[8] = {cur0.x, cur0.y, cur0.z, cur0.w, cur1.x, cur1.y, cur1.z, cur1.w};
        float ev[8], spl[8];
        #pragma unroll
        for (int i = 0; i < 8; ++i) {
            ev[i]  = h2f((unsigned short)(pk[i] & 0xFFFFu));
            spl[i] = h2f((unsigned short)(pk[i] >> 16));
        }

        float se = 0.f, sx = 0.f, sy = 0.f, sz = 0.f;
        #pragma unroll
        for (int i = 0; i < 8; ++i) {
            se += ev[i]; sx += ev[i] * cx[i]; sy += ev[i] * cy[i]; sz += ev[i] * cz[i];
        }
        float vals[4] = {se, sx, sy, sz};
        #pragma unroll
        for (int v = 0; v < 4; ++v) {
            float x = vals[v];
            #pragma unroll
            for (int o = 32; o > 0; o >>= 1) x += __shfl_down(x, o);
            if (lane == 0) redbuf[wid * 4 + v] = x;
        }
        __syncthreads();
        if (wid == 0) {
            float x = redbuf[lane];              // lane = w*4+v
            x += __shfl_down(x, 32);
            x += __shfl_down(x, 16);
            x += __shfl_down(x, 8);
            x += __shfl_down(x, 4);
            if (lane < 4) bcast[lane] = x;
        }
        __syncthreads();
        const float SE = bcast[0];
        const float AXc = bcast[1] / SE, AYc = bcast[2] / SE, AZc = bcast[3] / SE;

        const float* sm = &sums[((size_t)b * NMOD + m) * 8];
        float s  = fmaxf(sm[0], 1e-8f);
        float qw = sm[1] / s, qx = sm[2] / s, qy = sm[3] / s, qz = sm[4] / s;
        float qn = sqrtf(qw * qw + qx * qx + qy * qy + qz * qz);
        float qi = 1.f / fmaxf(qn, 1e-12f);
        qw *= qi; qx *= qi; qy *= qi; qz *= qi;
        float tgx = sm[5] / s, tgy = sm[6] / s, tgz = sm[7] / s;

        #pragma unroll
        for (int i = 0; i < 8; ++i) {
            float px = cx[i] - AXc, py = cy[i] - AYc, pz = cz[i] - AZc;
            float ux = qy * pz - qz * py;
            float uy = qz * px - qx * pz;
            float uz = qx * py - qy * px;
            float vx = qy * uz - qz * uy;
            float vy = qz * ux - qx * uz;
            float vz = qx * uy - qy * ux;
            float rx = px + 2.f * (qw * ux + vx);
            float ry = py + 2.f * (qw * uy + vy);
            float rz = pz + 2.f * (qw * uz + vz);
            float mx = rx + AXc + tgx, my = ry + AYc + tgy, mz = rz + AZc + tgz;
            float sp = spl[i];
            cx[i] += sp * (mx - cx[i]);
            cy[i] += sp * (my - cy[i]);
            cz[i] += sp * (mz - cz[i]);
        }
        cur0 = nxt0; cur1 = nxt1;
        __syncthreads();
    }

    {
        float c[24];
        #pragma unroll
        for (int i = 0; i < 8; ++i) { c[3*i] = cx[i]; c[3*i+1] = cy[i]; c[3*i+2] = cz[i]; }
        float4* op4 = reinterpret_cast<float4*>(&out[((size_t)b * NNODE + n0) * 3]);
        #pragma unroll
        for (int q = 0; q < 6; ++q)
            op4[q] = make_float4(c[q*4+0], c[q*4+1], c[q*4+2], c[q*4+3]);
    }
}

extern "C" void kernel_launch(void* const* d_in, const int* in_sizes, int n_in,
                              void* d_out, int out_size, void* d_ws, size_t ws_size,
                              hipStream_t stream) {
    const float* feats  = (const float*)d_in[0];
    const float* coords = (const float*)d_in[1];
    const float* W      = (const float*)d_in[2];
    const float* bias   = (const float*)d_in[3];
    float* out = (float*)d_out;

    char* ws = (char*)d_ws;
    unsigned short* Bpk = (unsigned short*)(ws);                  // 128 KB (256 KB reserved)
    unsigned int* esp   = (unsigned int*)(ws + 262144);           // 2 MB packed {sp|ew}
    float* sums         = (float*)(ws + 262144 + 2097152);        // 2 KB

    hipMemsetAsync(sums, 0, (size_t)BATCH * NMOD * 8 * sizeof(float), stream);
    pack_b<<<32, 256, 0, stream>>>(W, Bpk);
    gemm_mfma<<<256, 1024, 0, stream>>>(feats, Bpk, bias, esp, sums);
    scan_coords<<<BATCH, 1024, 0, stream>>>(coords, esp, sums, out);
}